// Round 9
// baseline (2696.912 us; speedup 1.0000x reference)
//
#include <hip/hip_runtime.h>
#include <math.h>

#define N_NODES 250000
#define N_EDGES 2500000
#define N_GRAPHS 512
#define BN_EPS 1e-5f
#define NT 500000   // 2*N_NODES degree/offset slots (F then B)
#define INV_N (1.0f / (float)N_NODES)

// ================= CSR build (per call; ws is re-poisoned every launch) =====

__global__ void k_deg(const int* __restrict__ src, const int* __restrict__ dst,
                      int* __restrict__ deg, int E)
{
    int e = blockIdx.x * blockDim.x + threadIdx.x;
    if (e >= E) return;
    atomicAdd(&deg[dst[e]], 1);            // F lists keyed by dst
    atomicAdd(&deg[N_NODES + src[e]], 1);  // B lists keyed by src
}

// block-level exclusive scan: 1024 elems/block (256 thr x 4)
__global__ void scan1(const int* __restrict__ deg, int* __restrict__ excl,
                      int* __restrict__ bsum, int n)
{
    __shared__ int s[256];
    int t = threadIdx.x, b = blockIdx.x;
    int base = b * 1024 + t * 4;
    int v[4]; int tsum = 0;
    #pragma unroll
    for (int i = 0; i < 4; i++) { v[i] = (base + i < n) ? deg[base + i] : 0; tsum += v[i]; }
    s[t] = tsum; __syncthreads();
    for (int o = 1; o < 256; o <<= 1) {
        int x = (t >= o) ? s[t - o] : 0; __syncthreads();
        s[t] += x; __syncthreads();
    }
    int run = s[t] - tsum;  // exclusive prefix of this thread's chunk
    #pragma unroll
    for (int i = 0; i < 4; i++) { if (base + i < n) excl[base + i] = run; run += v[i]; }
    if (t == 255) bsum[b] = s[255];
}

__global__ void scan2(const int* __restrict__ bsum, int* __restrict__ boff, int nb)
{
    __shared__ int s[512];
    int t = threadIdx.x;
    int v = (t < nb) ? bsum[t] : 0;
    s[t] = v; __syncthreads();
    for (int o = 1; o < 512; o <<= 1) {
        int x = (t >= o) ? s[t - o] : 0; __syncthreads();
        s[t] += x; __syncthreads();
    }
    if (t < nb) boff[t] = s[t] - v;
}

__global__ void scan3(const int* __restrict__ excl, const int* __restrict__ boff,
                      int* __restrict__ off, int n)
{
    int i = blockIdx.x * blockDim.x + threadIdx.x;
    if (i < n) off[i] = excl[i] + boff[i >> 10];
    if (i == 0) off[n] = 2 * N_EDGES;
}

__global__ void k_fill(const int* __restrict__ src, const int* __restrict__ dst,
                       const int* __restrict__ off, int* __restrict__ cur,
                       int* __restrict__ eidx, int E)
{
    int e = blockIdx.x * blockDim.x + threadIdx.x;
    if (e >= E) return;
    int s = src[e], d = dst[e];
    int pF = atomicAdd(&cur[d], 1);
    eidx[off[d] + pF] = s;
    int pB = atomicAdd(&cur[N_NODES + s], 1);
    eidx[off[N_NODES + s] + pB] = d;
}

// ============ fused per-layer: CSR gather + dual GIN MLP + BN stats =========
// Lane-per-feature: each half-wave (32 lanes) owns one node; lane f holds
// feature f as a scalar. gfx950 allocator rule (measured R4/R6/R7):
// VGPR cap = 256 / declared-waves-per-EU. (512,2) -> cap 128, same 16
// waves/CU occupancy as R6's (256,4)/cap-64, but room to keep 8 row loads
// in flight. The gather is ONE predicated 8-wide loop over the concatenated
// F+B neighbor list (both directions overlap; tails stay 8-deep). R8 showed
// bf16 rows don't cut fetch (128B line granularity) -> h stays fp32.
// Prev layer's BN folded algebraically into the consumer:
//   sum over (deg+1) rows of (a*v+b) = a*raw_sum + (deg+1)*b.

template <int DIN, bool BN_IN>
__global__ __launch_bounds__(512, 2)
void dgin_gather(const float* __restrict__ xin,
                 const int* __restrict__ off, const int* __restrict__ eidx,
                 const float* __restrict__ in_stats,   // prev layer raw sum/sumsq (BN_IN)
                 const float* __restrict__ in_g, const float* __restrict__ in_b,
                 const float* __restrict__ W1f, const float* __restrict__ b1f,
                 const float* __restrict__ W2f, const float* __restrict__ b2f,
                 const float* __restrict__ W1b, const float* __restrict__ b1b,
                 const float* __restrict__ W2b, const float* __restrict__ b2b,
                 float* __restrict__ out, float* __restrict__ stats, int ngroups)
{
    __shared__ float sW1[2][DIN * 32];
    __shared__ float sW2[2][32 * 32];
    __shared__ float sb1[2][32], sb2[2][32];
    __shared__ float sstat[64];

    int tid = threadIdx.x;
    for (int i = tid; i < DIN * 32; i += 512) { sW1[0][i] = W1f[i]; sW1[1][i] = W1b[i]; }
    for (int i = tid; i < 32 * 32;  i += 512) { sW2[0][i] = W2f[i]; sW2[1][i] = W2b[i]; }
    if (tid < 32) { sb1[0][tid] = b1f[tid]; sb1[1][tid] = b1b[tid];
                    sb2[0][tid] = b2f[tid]; sb2[1][tid] = b2b[tid]; }
    if (tid < 64) sstat[tid] = 0.f;
    __syncthreads();

    int f  = tid & 31;
    int hw = tid >> 5;          // half-wave id within block, 0..15

    // per-lane input-BN scale/shift (identity for layer 1)
    float scale = 1.f, shift = 0.f;
    if (BN_IN) {
        float mu  = in_stats[f] * INV_N;
        float var = in_stats[32 + f] * INV_N - mu * mu;
        scale = in_g[f] * rsqrtf(var + BN_EPS);
        shift = in_b[f] - mu * scale;
    }

    float bn_s = 0.f, bn_s2 = 0.f;

    for (int grp = blockIdx.x; grp < ngroups; grp += gridDim.x) {
        int node = grp * 16 + hw;

        float xr = (DIN == 32) ? xin[node * 32 + f]
                               : ((f < DIN) ? xin[node * DIN + f] : 0.f);

        int k0F = off[node],           k1F = off[node + 1];
        int k0B = off[N_NODES + node], k1B = off[N_NODES + node + 1];
        int degF = k1F - k0F, degB = k1B - k0B;
        int tot  = degF + degB;

        // 8-wide predicated gather over concatenated F+B lists:
        // 8 independent row loads in flight every iteration, both dirs overlap.
        float rF0 = 0.f, rF1 = 0.f, rF2 = 0.f, rF3 = 0.f;
        float rB0 = 0.f, rB1 = 0.f, rB2 = 0.f, rB3 = 0.f;
        for (int p = 0; p < tot; p += 8) {
            #pragma unroll
            for (int u = 0; u < 8; u++) {
                int q = p + u;
                bool act = (q < tot);
                bool isF = (q < degF);
                int kk = act ? (isF ? (k0F + q) : (k0B + q - degF)) : 0;
                int j = eidx[kk];
                float v = (DIN == 32) ? xin[j * 32 + f]
                                      : ((f < DIN) ? xin[j * DIN + f] : 0.f);
                float vF = (act && isF)  ? v : 0.f;
                float vB = (act && !isF) ? v : 0.f;
                switch (u & 3) {
                    case 0: rF0 += vF; rB0 += vB; break;
                    case 1: rF1 += vF; rB1 += vB; break;
                    case 2: rF2 += vF; rB2 += vB; break;
                    case 3: rF3 += vF; rB3 += vB; break;
                }
            }
        }
        float rawF = xr + ((rF0 + rF1) + (rF2 + rF3));
        float rawB = xr + ((rB0 + rB1) + (rB2 + rB3));

        // fold input BN: (deg+1) rows each transformed a*v+b
        float hinF = BN_IN ? fmaf(scale, rawF, (float)(degF + 1) * shift) : rawF;
        float hinB = BN_IN ? fmaf(scale, rawB, (float)(degB + 1) * shift) : rawB;

        float o = 0.f;
        #pragma unroll
        for (int dir = 0; dir < 2; dir++) {
            float hin = (dir == 0) ? hinF : hinB;

            float t1 = sb1[dir][f];
            #pragma unroll
            for (int i = 0; i < DIN; i++)
                t1 = fmaf(__shfl(hin, i, 32), sW1[dir][i * 32 + f], t1);
            t1 = fmaxf(t1, 0.f);

            float o2 = sb2[dir][f];
            #pragma unroll
            for (int i = 0; i < 32; i++)
                o2 = fmaf(__shfl(t1, i, 32), sW2[dir][i * 32 + f], o2);
            o += fmaxf(o2, 0.f);
        }
        o *= 0.5f;

        out[node * 32 + f] = o;             // raw (pre-BN) output, coalesced
        bn_s  += o;
        bn_s2 += o * o;
    }

    // BN stats of raw output: per-lane running sums -> LDS -> 64 global atomics
    atomicAdd(&sstat[f],      bn_s);
    atomicAdd(&sstat[32 + f], bn_s2);
    __syncthreads();
    if (tid < 64) atomicAdd(&stats[tid], sstat[tid]);
}

// ================= segmented mean-pool (batch is sorted) + head =============

__global__ void pool_seg(const float* __restrict__ h, const int* __restrict__ batch,
                         float* __restrict__ psum, float* __restrict__ pcnt, int n)
{
    int tid = threadIdx.x;
    int grp = tid >> 5, f = tid & 31;
    int base = blockIdx.x * 256;
    float acc = 0.f, cnt = 0.f;
    int curg = -1;
    for (int it = 0; it < 32; it++) {
        int nd = base + grp + it * 8;
        if (nd < n) {
            int g = batch[nd];
            if (g != curg) {
                if (curg >= 0) {
                    atomicAdd(&psum[curg * 32 + f], acc);
                    if (f == 0) atomicAdd(&pcnt[curg], cnt);
                }
                curg = g; acc = 0.f; cnt = 0.f;
            }
            acc += h[nd * 32 + f];
            cnt += 1.f;
        }
    }
    if (curg >= 0) {
        atomicAdd(&psum[curg * 32 + f], acc);
        if (f == 0) atomicAdd(&pcnt[curg], cnt);
    }
}

// head applies layer-3 BN to the pooled mean (mean of a*h+b = a*mean+b)

__global__ void head_kernel(const float* __restrict__ psum, const float* __restrict__ pcnt,
                            const float* __restrict__ stats3,
                            const float* __restrict__ g3, const float* __restrict__ b3,
                            const float* __restrict__ lbW, const float* __restrict__ lbb,
                            const float* __restrict__ lmW, const float* __restrict__ lmb,
                            float* __restrict__ out)
{
    int g = threadIdx.x;  // 512 threads, one block
    float cnt = fmaxf(pcnt[g], 1.0f);
    float inv = 1.0f / cnt;
    float p[32];
    #pragma unroll
    for (int i = 0; i < 32; i++) {
        float mu  = stats3[i] * INV_N;
        float var = stats3[32 + i] * INV_N - mu * mu;
        float a   = g3[i] * rsqrtf(var + BN_EPS);
        float b   = b3[i] - mu * a;
        p[i] = fmaf(a, psum[g * 32 + i] * inv, b);
    }
    float z = lmb[0];
    #pragma unroll
    for (int k = 0; k < 16; k++) {
        float acc = lbb[k];
        #pragma unroll
        for (int i = 0; i < 32; i++) acc += p[i] * lbW[i * 16 + k];
        z += fmaxf(acc, 0.0f) * lmW[k];
    }
    out[g] = 1.0f / (1.0f + expf(-z));
}

// ================= launcher =================================================

extern "C" void kernel_launch(void* const* d_in, const int* in_sizes, int n_in,
                              void* d_out, int out_size, void* d_ws, size_t ws_size,
                              hipStream_t stream)
{
    const float* x   = (const float*)d_in[0];
    const int* ei    = (const int*)d_in[1];
    const int* batch = (const int*)d_in[2];
    const int* src = ei;
    const int* dst = ei + N_EDGES;

    char* ws = (char*)d_ws;
    float* h_a    = (float*)(ws + 0);           // 32,000,000 B
    float* h_b    = (float*)(ws + 32000000);    // 32,000,000 B
    int*   eidx   = (int*)  (ws + 64000000);    // 20,000,000 B
    int*   off    = (int*)  (ws + 84000000);    // 2,000,004 B (NT+1 ints)
    int*   deg    = (int*)  (ws + 86000016);    // 2,000,000 B
    int*   cur    = (int*)  (ws + 88000016);    // 2,000,000 B
    int*   excl   = (int*)  (ws + 90000016);    // 2,000,000 B
    int*   bsum   = (int*)  (ws + 92000016);    // ~2 KB
    int*   boff   = (int*)  (ws + 92004016);    // ~2 KB
    float* stats1 = (float*)(ws + 92008016);    // 64 floats
    float* stats2 = (float*)(ws + 92008272);    // 64 floats
    float* stats3 = (float*)(ws + 92008528);    // 64 floats
    float* psum   = (float*)(ws + 92008784);    // 512*32 floats
    float* pcnt   = (float*)(ws + 92074320);    // 512 floats

    auto W = [&](int l, int j) { return (const float*)d_in[3 + (l - 1) * 10 + j]; };

    // ---- CSR build (both directions concatenated)
    hipMemsetAsync(deg, 0, NT * 4, stream);
    hipMemsetAsync(cur, 0, NT * 4, stream);
    k_deg<<<(N_EDGES + 255) / 256, 256, 0, stream>>>(src, dst, deg, N_EDGES);
    int nb = (NT + 1023) / 1024;  // 489
    scan1<<<nb, 256, 0, stream>>>(deg, excl, bsum, NT);
    scan2<<<1, 512, 0, stream>>>(bsum, boff, nb);
    scan3<<<(NT + 256) / 256, 256, 0, stream>>>(excl, boff, off, NT);
    k_fill<<<(N_EDGES + 255) / 256, 256, 0, stream>>>(src, dst, off, cur, eidx, N_EDGES);

    const int NGROUPS = N_NODES / 16;          // 15625 (exact)
    const int GRID_G  = 2048;

    hipMemsetAsync(stats1, 0, 64 * 4, stream);
    hipMemsetAsync(stats2, 0, 64 * 4, stream);
    hipMemsetAsync(stats3, 0, 64 * 4, stream);

    // ---- layer 1 (DIN=6, no input BN): x -> h_a (raw), stats1
    dgin_gather<6, false><<<GRID_G, 512, 0, stream>>>(
        x, off, eidx, nullptr, nullptr, nullptr,
        W(1,0), W(1,1), W(1,2), W(1,3), W(1,4), W(1,5), W(1,6), W(1,7),
        h_a, stats1, NGROUPS);

    // ---- layer 2: h_a (raw, BN1 folded) -> h_b (raw), stats2
    dgin_gather<32, true><<<GRID_G, 512, 0, stream>>>(
        h_a, off, eidx, stats1, W(1,8), W(1,9),
        W(2,0), W(2,1), W(2,2), W(2,3), W(2,4), W(2,5), W(2,6), W(2,7),
        h_b, stats2, NGROUPS);

    // ---- layer 3: h_b (raw, BN2 folded) -> h_a (raw), stats3
    dgin_gather<32, true><<<GRID_G, 512, 0, stream>>>(
        h_b, off, eidx, stats2, W(2,8), W(2,9),
        W(3,0), W(3,1), W(3,2), W(3,3), W(3,4), W(3,5), W(3,6), W(3,7),
        h_a, stats3, NGROUPS);

    // ---- pool raw h3 + head (BN3 folded into pooled mean)
    hipMemsetAsync(psum, 0, (size_t)N_GRAPHS * 32 * 4, stream);
    hipMemsetAsync(pcnt, 0, (size_t)N_GRAPHS * 4, stream);
    pool_seg<<<(N_NODES + 255) / 256, 256, 0, stream>>>(h_a, batch, psum, pcnt, N_NODES);
    head_kernel<<<1, 512, 0, stream>>>(psum, pcnt, stats3, W(3,8), W(3,9),
        (const float*)d_in[33], (const float*)d_in[34],
        (const float*)d_in[35], (const float*)d_in[36],
        (float*)d_out);
}

// Round 10
// 2584.926 us; speedup vs baseline: 1.0433x; 1.0433x over previous
//
#include <hip/hip_runtime.h>
#include <math.h>

#define N_NODES 250000
#define N_EDGES 2500000
#define N_GRAPHS 512
#define BN_EPS 1e-5f
#define NT 500000   // 2*N_NODES degree/offset slots (F then B)
#define INV_N (1.0f / (float)N_NODES)

// ================= CSR build (per call; ws is re-poisoned every launch) =====

__global__ void k_deg(const int* __restrict__ src, const int* __restrict__ dst,
                      int* __restrict__ deg, int E)
{
    int e = blockIdx.x * blockDim.x + threadIdx.x;
    if (e >= E) return;
    atomicAdd(&deg[dst[e]], 1);            // F lists keyed by dst
    atomicAdd(&deg[N_NODES + src[e]], 1);  // B lists keyed by src
}

// block-level exclusive scan: 1024 elems/block (256 thr x 4)
__global__ void scan1(const int* __restrict__ deg, int* __restrict__ excl,
                      int* __restrict__ bsum, int n)
{
    __shared__ int s[256];
    int t = threadIdx.x, b = blockIdx.x;
    int base = b * 1024 + t * 4;
    int v[4]; int tsum = 0;
    #pragma unroll
    for (int i = 0; i < 4; i++) { v[i] = (base + i < n) ? deg[base + i] : 0; tsum += v[i]; }
    s[t] = tsum; __syncthreads();
    for (int o = 1; o < 256; o <<= 1) {
        int x = (t >= o) ? s[t - o] : 0; __syncthreads();
        s[t] += x; __syncthreads();
    }
    int run = s[t] - tsum;  // exclusive prefix of this thread's chunk
    #pragma unroll
    for (int i = 0; i < 4; i++) { if (base + i < n) excl[base + i] = run; run += v[i]; }
    if (t == 255) bsum[b] = s[255];
}

__global__ void scan2(const int* __restrict__ bsum, int* __restrict__ boff, int nb)
{
    __shared__ int s[512];
    int t = threadIdx.x;
    int v = (t < nb) ? bsum[t] : 0;
    s[t] = v; __syncthreads();
    for (int o = 1; o < 512; o <<= 1) {
        int x = (t >= o) ? s[t - o] : 0; __syncthreads();
        s[t] += x; __syncthreads();
    }
    if (t < nb) boff[t] = s[t] - v;
}

__global__ void scan3(const int* __restrict__ excl, const int* __restrict__ boff,
                      int* __restrict__ off, int n)
{
    int i = blockIdx.x * blockDim.x + threadIdx.x;
    if (i < n) off[i] = excl[i] + boff[i >> 10];
    if (i == 0) off[n] = 2 * N_EDGES;
}

__global__ void k_fill(const int* __restrict__ src, const int* __restrict__ dst,
                       const int* __restrict__ off, int* __restrict__ cur,
                       int* __restrict__ eidx, int E)
{
    int e = blockIdx.x * blockDim.x + threadIdx.x;
    if (e >= E) return;
    int s = src[e], d = dst[e];
    int pF = atomicAdd(&cur[d], 1);
    eidx[off[d] + pF] = s;
    int pB = atomicAdd(&cur[N_NODES + s], 1);
    eidx[off[N_NODES + s] + pB] = d;
}

// ============ fused per-layer: CSR gather + dual GIN MLP + BN stats =========
// Lane-per-feature: each half-wave (32 lanes) owns one node; lane f holds
// feature f as a scalar. Gather: ONE predicated 8-wide loop over the
// concatenated F+B neighbor list (8 independent row loads in flight, both
// directions overlap, tails stay 8-deep) — R9 showed this drops memory-side
// FETCH 1.6 GB -> 0.3 GB (near-compulsory; h reused in cache). Block shape
// 256 threads: R9's 512-thread blocks halved achieved occupancy (22.7%,
// ~1 block/CU) and gave back the traffic win. (256,2) -> VGPR cap 128
// (usage ~104); achieved occupancy is VGPR-limited ~4 waves/SIMD = R6's.
// gfx950 allocator rule (measured R4/R6/R7): cap = 256/waves-per-EU.
// Prev layer's BN folded algebraically into the consumer:
//   sum over (deg+1) rows of (a*v+b) = a*raw_sum + (deg+1)*b.

template <int DIN, bool BN_IN>
__global__ __launch_bounds__(256, 2)
void dgin_gather(const float* __restrict__ xin,
                 const int* __restrict__ off, const int* __restrict__ eidx,
                 const float* __restrict__ in_stats,   // prev layer raw sum/sumsq (BN_IN)
                 const float* __restrict__ in_g, const float* __restrict__ in_b,
                 const float* __restrict__ W1f, const float* __restrict__ b1f,
                 const float* __restrict__ W2f, const float* __restrict__ b2f,
                 const float* __restrict__ W1b, const float* __restrict__ b1b,
                 const float* __restrict__ W2b, const float* __restrict__ b2b,
                 float* __restrict__ out, float* __restrict__ stats, int ngroups)
{
    __shared__ float sW1[2][DIN * 32];
    __shared__ float sW2[2][32 * 32];
    __shared__ float sb1[2][32], sb2[2][32];
    __shared__ float sstat[64];

    int tid = threadIdx.x;
    for (int i = tid; i < DIN * 32; i += 256) { sW1[0][i] = W1f[i]; sW1[1][i] = W1b[i]; }
    for (int i = tid; i < 32 * 32;  i += 256) { sW2[0][i] = W2f[i]; sW2[1][i] = W2b[i]; }
    if (tid < 32) { sb1[0][tid] = b1f[tid]; sb1[1][tid] = b1b[tid];
                    sb2[0][tid] = b2f[tid]; sb2[1][tid] = b2b[tid]; }
    if (tid < 64) sstat[tid] = 0.f;
    __syncthreads();

    int f  = tid & 31;
    int hw = tid >> 5;          // half-wave id within block, 0..7

    // per-lane input-BN scale/shift (identity for layer 1)
    float scale = 1.f, shift = 0.f;
    if (BN_IN) {
        float mu  = in_stats[f] * INV_N;
        float var = in_stats[32 + f] * INV_N - mu * mu;
        scale = in_g[f] * rsqrtf(var + BN_EPS);
        shift = in_b[f] - mu * scale;
    }

    float bn_s = 0.f, bn_s2 = 0.f;

    for (int grp = blockIdx.x; grp < ngroups; grp += gridDim.x) {
        int node = grp * 8 + hw;

        float xr = (DIN == 32) ? xin[node * 32 + f]
                               : ((f < DIN) ? xin[node * DIN + f] : 0.f);

        int k0F = off[node],           k1F = off[node + 1];
        int k0B = off[N_NODES + node], k1B = off[N_NODES + node + 1];
        int degF = k1F - k0F, degB = k1B - k0B;
        int tot  = degF + degB;

        // 8-wide predicated gather over concatenated F+B lists:
        // 8 independent row loads in flight every iteration, both dirs overlap.
        float rF0 = 0.f, rF1 = 0.f, rF2 = 0.f, rF3 = 0.f;
        float rB0 = 0.f, rB1 = 0.f, rB2 = 0.f, rB3 = 0.f;
        for (int p = 0; p < tot; p += 8) {
            #pragma unroll
            for (int u = 0; u < 8; u++) {
                int q = p + u;
                bool act = (q < tot);
                bool isF = (q < degF);
                int kk = act ? (isF ? (k0F + q) : (k0B + q - degF)) : 0;
                int j = eidx[kk];
                float v = (DIN == 32) ? xin[j * 32 + f]
                                      : ((f < DIN) ? xin[j * DIN + f] : 0.f);
                float vF = (act && isF)  ? v : 0.f;
                float vB = (act && !isF) ? v : 0.f;
                switch (u & 3) {
                    case 0: rF0 += vF; rB0 += vB; break;
                    case 1: rF1 += vF; rB1 += vB; break;
                    case 2: rF2 += vF; rB2 += vB; break;
                    case 3: rF3 += vF; rB3 += vB; break;
                }
            }
        }
        float rawF = xr + ((rF0 + rF1) + (rF2 + rF3));
        float rawB = xr + ((rB0 + rB1) + (rB2 + rB3));

        // fold input BN: (deg+1) rows each transformed a*v+b
        float hinF = BN_IN ? fmaf(scale, rawF, (float)(degF + 1) * shift) : rawF;
        float hinB = BN_IN ? fmaf(scale, rawB, (float)(degB + 1) * shift) : rawB;

        float o = 0.f;
        #pragma unroll
        for (int dir = 0; dir < 2; dir++) {
            float hin = (dir == 0) ? hinF : hinB;

            float t1 = sb1[dir][f];
            #pragma unroll
            for (int i = 0; i < DIN; i++)
                t1 = fmaf(__shfl(hin, i, 32), sW1[dir][i * 32 + f], t1);
            t1 = fmaxf(t1, 0.f);

            float o2 = sb2[dir][f];
            #pragma unroll
            for (int i = 0; i < 32; i++)
                o2 = fmaf(__shfl(t1, i, 32), sW2[dir][i * 32 + f], o2);
            o += fmaxf(o2, 0.f);
        }
        o *= 0.5f;

        out[node * 32 + f] = o;             // raw (pre-BN) output, coalesced
        bn_s  += o;
        bn_s2 += o * o;
    }

    // BN stats of raw output: per-lane running sums -> LDS -> 64 global atomics
    atomicAdd(&sstat[f],      bn_s);
    atomicAdd(&sstat[32 + f], bn_s2);
    __syncthreads();
    if (tid < 64) atomicAdd(&stats[tid], sstat[tid]);
}

// ================= segmented mean-pool (batch is sorted) + head =============

__global__ void pool_seg(const float* __restrict__ h, const int* __restrict__ batch,
                         float* __restrict__ psum, float* __restrict__ pcnt, int n)
{
    int tid = threadIdx.x;
    int grp = tid >> 5, f = tid & 31;
    int base = blockIdx.x * 256;
    float acc = 0.f, cnt = 0.f;
    int curg = -1;
    for (int it = 0; it < 32; it++) {
        int nd = base + grp + it * 8;
        if (nd < n) {
            int g = batch[nd];
            if (g != curg) {
                if (curg >= 0) {
                    atomicAdd(&psum[curg * 32 + f], acc);
                    if (f == 0) atomicAdd(&pcnt[curg], cnt);
                }
                curg = g; acc = 0.f; cnt = 0.f;
            }
            acc += h[nd * 32 + f];
            cnt += 1.f;
        }
    }
    if (curg >= 0) {
        atomicAdd(&psum[curg * 32 + f], acc);
        if (f == 0) atomicAdd(&pcnt[curg], cnt);
    }
}

// head applies layer-3 BN to the pooled mean (mean of a*h+b = a*mean+b)

__global__ void head_kernel(const float* __restrict__ psum, const float* __restrict__ pcnt,
                            const float* __restrict__ stats3,
                            const float* __restrict__ g3, const float* __restrict__ b3,
                            const float* __restrict__ lbW, const float* __restrict__ lbb,
                            const float* __restrict__ lmW, const float* __restrict__ lmb,
                            float* __restrict__ out)
{
    int g = threadIdx.x;  // 512 threads, one block
    float cnt = fmaxf(pcnt[g], 1.0f);
    float inv = 1.0f / cnt;
    float p[32];
    #pragma unroll
    for (int i = 0; i < 32; i++) {
        float mu  = stats3[i] * INV_N;
        float var = stats3[32 + i] * INV_N - mu * mu;
        float a   = g3[i] * rsqrtf(var + BN_EPS);
        float b   = b3[i] - mu * a;
        p[i] = fmaf(a, psum[g * 32 + i] * inv, b);
    }
    float z = lmb[0];
    #pragma unroll
    for (int k = 0; k < 16; k++) {
        float acc = lbb[k];
        #pragma unroll
        for (int i = 0; i < 32; i++) acc += p[i] * lbW[i * 16 + k];
        z += fmaxf(acc, 0.0f) * lmW[k];
    }
    out[g] = 1.0f / (1.0f + expf(-z));
}

// ================= launcher =================================================

extern "C" void kernel_launch(void* const* d_in, const int* in_sizes, int n_in,
                              void* d_out, int out_size, void* d_ws, size_t ws_size,
                              hipStream_t stream)
{
    const float* x   = (const float*)d_in[0];
    const int* ei    = (const int*)d_in[1];
    const int* batch = (const int*)d_in[2];
    const int* src = ei;
    const int* dst = ei + N_EDGES;

    char* ws = (char*)d_ws;
    float* h_a    = (float*)(ws + 0);           // 32,000,000 B
    float* h_b    = (float*)(ws + 32000000);    // 32,000,000 B
    int*   eidx   = (int*)  (ws + 64000000);    // 20,000,000 B
    int*   off    = (int*)  (ws + 84000000);    // 2,000,004 B (NT+1 ints)
    int*   deg    = (int*)  (ws + 86000016);    // 2,000,000 B
    int*   cur    = (int*)  (ws + 88000016);    // 2,000,000 B
    int*   excl   = (int*)  (ws + 90000016);    // 2,000,000 B
    int*   bsum   = (int*)  (ws + 92000016);    // ~2 KB
    int*   boff   = (int*)  (ws + 92004016);    // ~2 KB
    float* stats1 = (float*)(ws + 92008016);    // 64 floats
    float* stats2 = (float*)(ws + 92008272);    // 64 floats
    float* stats3 = (float*)(ws + 92008528);    // 64 floats
    float* psum   = (float*)(ws + 92008784);    // 512*32 floats
    float* pcnt   = (float*)(ws + 92074320);    // 512 floats

    auto W = [&](int l, int j) { return (const float*)d_in[3 + (l - 1) * 10 + j]; };

    // ---- CSR build (both directions concatenated)
    hipMemsetAsync(deg, 0, NT * 4, stream);
    hipMemsetAsync(cur, 0, NT * 4, stream);
    k_deg<<<(N_EDGES + 255) / 256, 256, 0, stream>>>(src, dst, deg, N_EDGES);
    int nb = (NT + 1023) / 1024;  // 489
    scan1<<<nb, 256, 0, stream>>>(deg, excl, bsum, NT);
    scan2<<<1, 512, 0, stream>>>(bsum, boff, nb);
    scan3<<<(NT + 256) / 256, 256, 0, stream>>>(excl, boff, off, NT);
    k_fill<<<(N_EDGES + 255) / 256, 256, 0, stream>>>(src, dst, off, cur, eidx, N_EDGES);

    const int NGROUPS = N_NODES / 8;           // 31250 (exact)
    const int GRID_G  = 4096;

    hipMemsetAsync(stats1, 0, 64 * 4, stream);
    hipMemsetAsync(stats2, 0, 64 * 4, stream);
    hipMemsetAsync(stats3, 0, 64 * 4, stream);

    // ---- layer 1 (DIN=6, no input BN): x -> h_a (raw), stats1
    dgin_gather<6, false><<<GRID_G, 256, 0, stream>>>(
        x, off, eidx, nullptr, nullptr, nullptr,
        W(1,0), W(1,1), W(1,2), W(1,3), W(1,4), W(1,5), W(1,6), W(1,7),
        h_a, stats1, NGROUPS);

    // ---- layer 2: h_a (raw, BN1 folded) -> h_b (raw), stats2
    dgin_gather<32, true><<<GRID_G, 256, 0, stream>>>(
        h_a, off, eidx, stats1, W(1,8), W(1,9),
        W(2,0), W(2,1), W(2,2), W(2,3), W(2,4), W(2,5), W(2,6), W(2,7),
        h_b, stats2, NGROUPS);

    // ---- layer 3: h_b (raw, BN2 folded) -> h_a (raw), stats3
    dgin_gather<32, true><<<GRID_G, 256, 0, stream>>>(
        h_b, off, eidx, stats2, W(2,8), W(2,9),
        W(3,0), W(3,1), W(3,2), W(3,3), W(3,4), W(3,5), W(3,6), W(3,7),
        h_a, stats3, NGROUPS);

    // ---- pool raw h3 + head (BN3 folded into pooled mean)
    hipMemsetAsync(psum, 0, (size_t)N_GRAPHS * 32 * 4, stream);
    hipMemsetAsync(pcnt, 0, (size_t)N_GRAPHS * 4, stream);
    pool_seg<<<(N_NODES + 255) / 256, 256, 0, stream>>>(h_a, batch, psum, pcnt, N_NODES);
    head_kernel<<<1, 512, 0, stream>>>(psum, pcnt, stats3, W(3,8), W(3,9),
        (const float*)d_in[33], (const float*)d_in[34],
        (const float*)d_in[35], (const float*)d_in[36],
        (float*)d_out);
}

// Round 11
// 2115.811 us; speedup vs baseline: 1.2746x; 1.2217x over previous
//
#include <hip/hip_runtime.h>
#include <math.h>

#define N_NODES 250000
#define N_EDGES 2500000
#define N_GRAPHS 512
#define BN_EPS 1e-5f
#define NT 500000   // 2*N_NODES degree/offset slots (F then B)
#define INV_N (1.0f / (float)N_NODES)

// ================= CSR build (per call; ws is re-poisoned every launch) =====

__global__ void k_deg(const int* __restrict__ src, const int* __restrict__ dst,
                      int* __restrict__ deg, int E)
{
    int e = blockIdx.x * blockDim.x + threadIdx.x;
    if (e >= E) return;
    atomicAdd(&deg[dst[e]], 1);            // F lists keyed by dst
    atomicAdd(&deg[N_NODES + src[e]], 1);  // B lists keyed by src
}

__global__ void scan1(const int* __restrict__ deg, int* __restrict__ excl,
                      int* __restrict__ bsum, int n)
{
    __shared__ int s[256];
    int t = threadIdx.x, b = blockIdx.x;
    int base = b * 1024 + t * 4;
    int v[4]; int tsum = 0;
    #pragma unroll
    for (int i = 0; i < 4; i++) { v[i] = (base + i < n) ? deg[base + i] : 0; tsum += v[i]; }
    s[t] = tsum; __syncthreads();
    for (int o = 1; o < 256; o <<= 1) {
        int x = (t >= o) ? s[t - o] : 0; __syncthreads();
        s[t] += x; __syncthreads();
    }
    int run = s[t] - tsum;
    #pragma unroll
    for (int i = 0; i < 4; i++) { if (base + i < n) excl[base + i] = run; run += v[i]; }
    if (t == 255) bsum[b] = s[255];
}

__global__ void scan2(const int* __restrict__ bsum, int* __restrict__ boff, int nb)
{
    __shared__ int s[512];
    int t = threadIdx.x;
    int v = (t < nb) ? bsum[t] : 0;
    s[t] = v; __syncthreads();
    for (int o = 1; o < 512; o <<= 1) {
        int x = (t >= o) ? s[t - o] : 0; __syncthreads();
        s[t] += x; __syncthreads();
    }
    if (t < nb) boff[t] = s[t] - v;
}

__global__ void scan3(const int* __restrict__ excl, const int* __restrict__ boff,
                      int* __restrict__ off, int n)
{
    int i = blockIdx.x * blockDim.x + threadIdx.x;
    if (i < n) off[i] = excl[i] + boff[i >> 10];
    if (i == 0) off[n] = 2 * N_EDGES;
}

__global__ void k_fill(const int* __restrict__ src, const int* __restrict__ dst,
                       const int* __restrict__ off, int* __restrict__ cur,
                       int* __restrict__ eidx, int E)
{
    int e = blockIdx.x * blockDim.x + threadIdx.x;
    if (e >= E) return;
    int s = src[e], d = dst[e];
    int pF = atomicAdd(&cur[d], 1);
    eidx[off[d] + pF] = s;
    int pB = atomicAdd(&cur[N_NODES + s], 1);
    eidx[off[N_NODES + s] + pB] = d;
}

// ================= SPLIT PATH ===============================================
// gather_nbr: pure neighbor-sum (no MLP) over the concatenated 2N CSR lists.
// Small live set -> VGPR <= 64 -> 4+ waves/SIMD (gfx950 law measured R4-R10:
// waves/SIMD ~ floor(256/VGPR)), and ~100% memory duty (no VALU phase).
// 8-wide predicated loop keeps 8 row loads in flight incl. tails (R9-proven
// shape: FETCH near-compulsory 0.3 GB).

template <int DIN>
__global__ __launch_bounds__(256, 4)
void gather_nbr(const float* __restrict__ xin, const int* __restrict__ off,
                const int* __restrict__ eidx, float* __restrict__ agg, int ngroups)
{
    int tid = threadIdx.x;
    int f = tid & 31, hw = tid >> 5;
    for (int grp = blockIdx.x; grp < ngroups; grp += gridDim.x) {
        int u = grp * 8 + hw;                 // list id in [0, 2N)
        int k0 = off[u], k1 = off[u + 1];
        float r0 = 0.f, r1 = 0.f, r2 = 0.f, r3 = 0.f;
        for (int p = k0; p < k1; p += 8) {
            #pragma unroll
            for (int q = 0; q < 8; q++) {
                int kk = p + q;
                bool act = (kk < k1);
                int j = eidx[act ? kk : k0];
                float v;
                if (DIN == 32) v = xin[j * 32 + f];
                else           v = (f < DIN) ? xin[j * DIN + f] : 0.f;
                v = act ? v : 0.f;
                if ((q & 3) == 0)      r0 += v;
                else if ((q & 3) == 1) r1 += v;
                else if ((q & 3) == 2) r2 += v;
                else                   r3 += v;
            }
        }
        float s = (r0 + r1) + (r2 + r3);
        if (DIN == 32)      agg[u * 32 + f] = s;
        else if (f < DIN)   agg[u * DIN + f] = s;
    }
}

// dgin_mlp: streaming (coalesced) dual-direction GIN MLP + BN stats.
// Reads self row + aggF/aggB + degrees; writes h IN PLACE (safe: neighbor
// data already captured in agg). Prev layer's BN folded algebraically:
//   sum over (deg+1) rows of (a*v+b) = a*raw_sum + (deg+1)*b.
// NOTE: xin/out may alias (in-place) -> no __restrict__ on them.

template <int DIN, bool BN_IN>
__global__ __launch_bounds__(256, 4)
void dgin_mlp(const float* xin, const float* __restrict__ agg,
              const int* __restrict__ off,
              const float* __restrict__ in_stats,
              const float* __restrict__ in_g, const float* __restrict__ in_b,
              const float* __restrict__ W1f, const float* __restrict__ b1f,
              const float* __restrict__ W2f, const float* __restrict__ b2f,
              const float* __restrict__ W1b, const float* __restrict__ b1b,
              const float* __restrict__ W2b, const float* __restrict__ b2b,
              float* out, float* __restrict__ stats, int ngroups)
{
    __shared__ float sW1[2][DIN * 32];
    __shared__ float sW2[2][32 * 32];
    __shared__ float sb1[2][32], sb2[2][32];
    __shared__ float sstat[64];

    int tid = threadIdx.x;
    for (int i = tid; i < DIN * 32; i += 256) { sW1[0][i] = W1f[i]; sW1[1][i] = W1b[i]; }
    for (int i = tid; i < 32 * 32;  i += 256) { sW2[0][i] = W2f[i]; sW2[1][i] = W2b[i]; }
    if (tid < 32) { sb1[0][tid] = b1f[tid]; sb1[1][tid] = b1b[tid];
                    sb2[0][tid] = b2f[tid]; sb2[1][tid] = b2b[tid]; }
    if (tid < 64) sstat[tid] = 0.f;
    __syncthreads();

    int f  = tid & 31;
    int hw = tid >> 5;

    float scale = 1.f, shift = 0.f;
    if (BN_IN) {
        float mu  = in_stats[f] * INV_N;
        float var = in_stats[32 + f] * INV_N - mu * mu;
        scale = in_g[f] * rsqrtf(var + BN_EPS);
        shift = in_b[f] - mu * scale;
    }

    float bn_s = 0.f, bn_s2 = 0.f;

    for (int grp = blockIdx.x; grp < ngroups; grp += gridDim.x) {
        int node = grp * 8 + hw;

        float xr, aF, aB;
        if (DIN == 32) {
            xr = xin[node * 32 + f];
            aF = agg[node * 32 + f];
            aB = agg[(N_NODES + node) * 32 + f];
        } else {
            xr = (f < DIN) ? xin[node * DIN + f] : 0.f;
            aF = (f < DIN) ? agg[node * DIN + f] : 0.f;
            aB = (f < DIN) ? agg[(N_NODES + node) * DIN + f] : 0.f;
        }
        int degF = off[node + 1] - off[node];
        int degB = off[N_NODES + node + 1] - off[N_NODES + node];

        float rawF = xr + aF;
        float rawB = xr + aB;
        float hinF = BN_IN ? fmaf(scale, rawF, (float)(degF + 1) * shift) : rawF;
        float hinB = BN_IN ? fmaf(scale, rawB, (float)(degB + 1) * shift) : rawB;

        float o = 0.f;
        #pragma unroll
        for (int dir = 0; dir < 2; dir++) {
            float hin = (dir == 0) ? hinF : hinB;

            float t1 = sb1[dir][f];
            #pragma unroll
            for (int i = 0; i < DIN; i++)
                t1 = fmaf(__shfl(hin, i, 32), sW1[dir][i * 32 + f], t1);
            t1 = fmaxf(t1, 0.f);

            float o2 = sb2[dir][f];
            #pragma unroll
            for (int i = 0; i < 32; i++)
                o2 = fmaf(__shfl(t1, i, 32), sW2[dir][i * 32 + f], o2);
            o += fmaxf(o2, 0.f);
        }
        o *= 0.5f;

        out[node * 32 + f] = o;
        bn_s  += o;
        bn_s2 += o * o;
    }

    atomicAdd(&sstat[f],      bn_s);
    atomicAdd(&sstat[32 + f], bn_s2);
    __syncthreads();
    if (tid < 64) atomicAdd(&stats[tid], sstat[tid]);
}

// ================= FUSED PATH (R10 fallback, used if ws too small) ==========

template <int DIN, bool BN_IN>
__global__ __launch_bounds__(256, 2)
void dgin_gather(const float* __restrict__ xin,
                 const int* __restrict__ off, const int* __restrict__ eidx,
                 const float* __restrict__ in_stats,
                 const float* __restrict__ in_g, const float* __restrict__ in_b,
                 const float* __restrict__ W1f, const float* __restrict__ b1f,
                 const float* __restrict__ W2f, const float* __restrict__ b2f,
                 const float* __restrict__ W1b, const float* __restrict__ b1b,
                 const float* __restrict__ W2b, const float* __restrict__ b2b,
                 float* __restrict__ out, float* __restrict__ stats, int ngroups)
{
    __shared__ float sW1[2][DIN * 32];
    __shared__ float sW2[2][32 * 32];
    __shared__ float sb1[2][32], sb2[2][32];
    __shared__ float sstat[64];

    int tid = threadIdx.x;
    for (int i = tid; i < DIN * 32; i += 256) { sW1[0][i] = W1f[i]; sW1[1][i] = W1b[i]; }
    for (int i = tid; i < 32 * 32;  i += 256) { sW2[0][i] = W2f[i]; sW2[1][i] = W2b[i]; }
    if (tid < 32) { sb1[0][tid] = b1f[tid]; sb1[1][tid] = b1b[tid];
                    sb2[0][tid] = b2f[tid]; sb2[1][tid] = b2b[tid]; }
    if (tid < 64) sstat[tid] = 0.f;
    __syncthreads();

    int f  = tid & 31;
    int hw = tid >> 5;

    float scale = 1.f, shift = 0.f;
    if (BN_IN) {
        float mu  = in_stats[f] * INV_N;
        float var = in_stats[32 + f] * INV_N - mu * mu;
        scale = in_g[f] * rsqrtf(var + BN_EPS);
        shift = in_b[f] - mu * scale;
    }

    float bn_s = 0.f, bn_s2 = 0.f;

    for (int grp = blockIdx.x; grp < ngroups; grp += gridDim.x) {
        int node = grp * 8 + hw;

        float xr = (DIN == 32) ? xin[node * 32 + f]
                               : ((f < DIN) ? xin[node * DIN + f] : 0.f);

        int k0F = off[node],           k1F = off[node + 1];
        int k0B = off[N_NODES + node], k1B = off[N_NODES + node + 1];
        int degF = k1F - k0F, degB = k1B - k0B;
        int tot  = degF + degB;

        float rF0 = 0.f, rF1 = 0.f, rF2 = 0.f, rF3 = 0.f;
        float rB0 = 0.f, rB1 = 0.f, rB2 = 0.f, rB3 = 0.f;
        for (int p = 0; p < tot; p += 8) {
            #pragma unroll
            for (int u = 0; u < 8; u++) {
                int q = p + u;
                bool act = (q < tot);
                bool isF = (q < degF);
                int kk = act ? (isF ? (k0F + q) : (k0B + q - degF)) : 0;
                int j = eidx[kk];
                float v = (DIN == 32) ? xin[j * 32 + f]
                                      : ((f < DIN) ? xin[j * DIN + f] : 0.f);
                float vF = (act && isF)  ? v : 0.f;
                float vB = (act && !isF) ? v : 0.f;
                switch (u & 3) {
                    case 0: rF0 += vF; rB0 += vB; break;
                    case 1: rF1 += vF; rB1 += vB; break;
                    case 2: rF2 += vF; rB2 += vB; break;
                    case 3: rF3 += vF; rB3 += vB; break;
                }
            }
        }
        float rawF = xr + ((rF0 + rF1) + (rF2 + rF3));
        float rawB = xr + ((rB0 + rB1) + (rB2 + rB3));

        float hinF = BN_IN ? fmaf(scale, rawF, (float)(degF + 1) * shift) : rawF;
        float hinB = BN_IN ? fmaf(scale, rawB, (float)(degB + 1) * shift) : rawB;

        float o = 0.f;
        #pragma unroll
        for (int dir = 0; dir < 2; dir++) {
            float hin = (dir == 0) ? hinF : hinB;

            float t1 = sb1[dir][f];
            #pragma unroll
            for (int i = 0; i < DIN; i++)
                t1 = fmaf(__shfl(hin, i, 32), sW1[dir][i * 32 + f], t1);
            t1 = fmaxf(t1, 0.f);

            float o2 = sb2[dir][f];
            #pragma unroll
            for (int i = 0; i < 32; i++)
                o2 = fmaf(__shfl(t1, i, 32), sW2[dir][i * 32 + f], o2);
            o += fmaxf(o2, 0.f);
        }
        o *= 0.5f;

        out[node * 32 + f] = o;
        bn_s  += o;
        bn_s2 += o * o;
    }

    atomicAdd(&sstat[f],      bn_s);
    atomicAdd(&sstat[32 + f], bn_s2);
    __syncthreads();
    if (tid < 64) atomicAdd(&stats[tid], sstat[tid]);
}

// ================= segmented mean-pool (batch is sorted) + head =============

__global__ void pool_seg(const float* __restrict__ h, const int* __restrict__ batch,
                         float* __restrict__ psum, float* __restrict__ pcnt, int n)
{
    int tid = threadIdx.x;
    int grp = tid >> 5, f = tid & 31;
    int base = blockIdx.x * 256;
    float acc = 0.f, cnt = 0.f;
    int curg = -1;
    for (int it = 0; it < 32; it++) {
        int nd = base + grp + it * 8;
        if (nd < n) {
            int g = batch[nd];
            if (g != curg) {
                if (curg >= 0) {
                    atomicAdd(&psum[curg * 32 + f], acc);
                    if (f == 0) atomicAdd(&pcnt[curg], cnt);
                }
                curg = g; acc = 0.f; cnt = 0.f;
            }
            acc += h[nd * 32 + f];
            cnt += 1.f;
        }
    }
    if (curg >= 0) {
        atomicAdd(&psum[curg * 32 + f], acc);
        if (f == 0) atomicAdd(&pcnt[curg], cnt);
    }
}

__global__ void head_kernel(const float* __restrict__ psum, const float* __restrict__ pcnt,
                            const float* __restrict__ stats3,
                            const float* __restrict__ g3, const float* __restrict__ b3,
                            const float* __restrict__ lbW, const float* __restrict__ lbb,
                            const float* __restrict__ lmW, const float* __restrict__ lmb,
                            float* __restrict__ out)
{
    int g = threadIdx.x;  // 512 threads, one block
    float cnt = fmaxf(pcnt[g], 1.0f);
    float inv = 1.0f / cnt;
    float p[32];
    #pragma unroll
    for (int i = 0; i < 32; i++) {
        float mu  = stats3[i] * INV_N;
        float var = stats3[32 + i] * INV_N - mu * mu;
        float a   = g3[i] * rsqrtf(var + BN_EPS);
        float b   = b3[i] - mu * a;
        p[i] = fmaf(a, psum[g * 32 + i] * inv, b);
    }
    float z = lmb[0];
    #pragma unroll
    for (int k = 0; k < 16; k++) {
        float acc = lbb[k];
        #pragma unroll
        for (int i = 0; i < 32; i++) acc += p[i] * lbW[i * 16 + k];
        z += fmaxf(acc, 0.0f) * lmW[k];
    }
    out[g] = 1.0f / (1.0f + expf(-z));
}

// ================= launcher =================================================

extern "C" void kernel_launch(void* const* d_in, const int* in_sizes, int n_in,
                              void* d_out, int out_size, void* d_ws, size_t ws_size,
                              hipStream_t stream)
{
    const float* x   = (const float*)d_in[0];
    const int* ei    = (const int*)d_in[1];
    const int* batch = (const int*)d_in[2];
    const int* src = ei;
    const int* dst = ei + N_EDGES;
    char* ws = (char*)d_ws;

    auto W = [&](int l, int j) { return (const float*)d_in[3 + (l - 1) * 10 + j]; };

    const size_t NEED_SPLIT = 118068368;  // split-path layout size

    if (ws_size >= NEED_SPLIT) {
        // ---------------- split path ----------------
        float* h    = (float*)(ws + 0);            // 32 MB
        float* agg  = (float*)(ws + 32000000);     // 64 MB (2N x 32 fp32)
        int*   eidx = (int*)  (ws + 96000000);     // 20 MB
        int*   off  = (int*)  (ws + 116000000);    // (NT+1) ints
        // CSR-build temps live inside the agg region (dead after k_fill)
        int*   deg  = (int*)  (ws + 32000000);
        int*   cur  = (int*)  (ws + 34000016);
        int*   excl = (int*)  (ws + 36000016);
        int*   bsum = (int*)  (ws + 38000016);
        int*   boff = (int*)  (ws + 38004016);
        float* stats1 = (float*)(ws + 118000016);
        float* stats2 = stats1 + 64;
        float* stats3 = stats1 + 128;
        float* psum   = (float*)(ws + 118000784);
        float* pcnt   = (float*)(ws + 118066320);

        hipMemsetAsync(deg, 0, NT * 4, stream);
        hipMemsetAsync(cur, 0, NT * 4, stream);
        k_deg<<<(N_EDGES + 255) / 256, 256, 0, stream>>>(src, dst, deg, N_EDGES);
        int nb = (NT + 1023) / 1024;
        scan1<<<nb, 256, 0, stream>>>(deg, excl, bsum, NT);
        scan2<<<1, 512, 0, stream>>>(bsum, boff, nb);
        scan3<<<(NT + 256) / 256, 256, 0, stream>>>(excl, boff, off, NT);
        k_fill<<<(N_EDGES + 255) / 256, 256, 0, stream>>>(src, dst, off, cur, eidx, N_EDGES);

        hipMemsetAsync(stats1, 0, 3 * 64 * 4, stream);

        const int GG = 4096;
        const int UG = NT / 8;        // 62500 gather groups (2N lists)
        const int NG = N_NODES / 8;   // 31250 mlp groups

        // layer 1 (DIN=6): x -> h, stats1
        gather_nbr<6><<<GG, 256, 0, stream>>>(x, off, eidx, agg, UG);
        dgin_mlp<6, false><<<GG, 256, 0, stream>>>(
            x, agg, off, nullptr, nullptr, nullptr,
            W(1,0), W(1,1), W(1,2), W(1,3), W(1,4), W(1,5), W(1,6), W(1,7),
            h, stats1, NG);

        // layer 2: h -> h (in place), stats2
        gather_nbr<32><<<GG, 256, 0, stream>>>(h, off, eidx, agg, UG);
        dgin_mlp<32, true><<<GG, 256, 0, stream>>>(
            h, agg, off, stats1, W(1,8), W(1,9),
            W(2,0), W(2,1), W(2,2), W(2,3), W(2,4), W(2,5), W(2,6), W(2,7),
            h, stats2, NG);

        // layer 3: h -> h (in place), stats3
        gather_nbr<32><<<GG, 256, 0, stream>>>(h, off, eidx, agg, UG);
        dgin_mlp<32, true><<<GG, 256, 0, stream>>>(
            h, agg, off, stats2, W(2,8), W(2,9),
            W(3,0), W(3,1), W(3,2), W(3,3), W(3,4), W(3,5), W(3,6), W(3,7),
            h, stats3, NG);

        hipMemsetAsync(psum, 0, (size_t)N_GRAPHS * 32 * 4, stream);
        hipMemsetAsync(pcnt, 0, (size_t)N_GRAPHS * 4, stream);
        pool_seg<<<(N_NODES + 255) / 256, 256, 0, stream>>>(h, batch, psum, pcnt, N_NODES);
        head_kernel<<<1, 512, 0, stream>>>(psum, pcnt, stats3, W(3,8), W(3,9),
            (const float*)d_in[33], (const float*)d_in[34],
            (const float*)d_in[35], (const float*)d_in[36],
            (float*)d_out);
    } else {
        // ---------------- fused fallback (R10) ----------------
        float* h_a    = (float*)(ws + 0);
        float* h_b    = (float*)(ws + 32000000);
        int*   eidx   = (int*)  (ws + 64000000);
        int*   off    = (int*)  (ws + 84000000);
        int*   deg    = (int*)  (ws + 86000016);
        int*   cur    = (int*)  (ws + 88000016);
        int*   excl   = (int*)  (ws + 90000016);
        int*   bsum   = (int*)  (ws + 92000016);
        int*   boff   = (int*)  (ws + 92004016);
        float* stats1 = (float*)(ws + 92008016);
        float* stats2 = (float*)(ws + 92008272);
        float* stats3 = (float*)(ws + 92008528);
        float* psum   = (float*)(ws + 92008784);
        float* pcnt   = (float*)(ws + 92074320);

        hipMemsetAsync(deg, 0, NT * 4, stream);
        hipMemsetAsync(cur, 0, NT * 4, stream);
        k_deg<<<(N_EDGES + 255) / 256, 256, 0, stream>>>(src, dst, deg, N_EDGES);
        int nb = (NT + 1023) / 1024;
        scan1<<<nb, 256, 0, stream>>>(deg, excl, bsum, NT);
        scan2<<<1, 512, 0, stream>>>(bsum, boff, nb);
        scan3<<<(NT + 256) / 256, 256, 0, stream>>>(excl, boff, off, NT);
        k_fill<<<(N_EDGES + 255) / 256, 256, 0, stream>>>(src, dst, off, cur, eidx, N_EDGES);

        const int NGROUPS = N_NODES / 8;
        const int GRID_G  = 4096;

        hipMemsetAsync(stats1, 0, 64 * 4, stream);
        hipMemsetAsync(stats2, 0, 64 * 4, stream);
        hipMemsetAsync(stats3, 0, 64 * 4, stream);

        dgin_gather<6, false><<<GRID_G, 256, 0, stream>>>(
            x, off, eidx, nullptr, nullptr, nullptr,
            W(1,0), W(1,1), W(1,2), W(1,3), W(1,4), W(1,5), W(1,6), W(1,7),
            h_a, stats1, NGROUPS);
        dgin_gather<32, true><<<GRID_G, 256, 0, stream>>>(
            h_a, off, eidx, stats1, W(1,8), W(1,9),
            W(2,0), W(2,1), W(2,2), W(2,3), W(2,4), W(2,5), W(2,6), W(2,7),
            h_b, stats2, NGROUPS);
        dgin_gather<32, true><<<GRID_G, 256, 0, stream>>>(
            h_b, off, eidx, stats2, W(2,8), W(2,9),
            W(3,0), W(3,1), W(3,2), W(3,3), W(3,4), W(3,5), W(3,6), W(3,7),
            h_a, stats3, NGROUPS);

        hipMemsetAsync(psum, 0, (size_t)N_GRAPHS * 32 * 4, stream);
        hipMemsetAsync(pcnt, 0, (size_t)N_GRAPHS * 4, stream);
        pool_seg<<<(N_NODES + 255) / 256, 256, 0, stream>>>(h_a, batch, psum, pcnt, N_NODES);
        head_kernel<<<1, 512, 0, stream>>>(psum, pcnt, stats3, W(3,8), W(3,9),
            (const float*)d_in[33], (const float*)d_in[34],
            (const float*)d_in[35], (const float*)d_in[36],
            (float*)d_out);
    }
}